// Round 10
// baseline (350.077 us; speedup 1.0000x reference)
//
#include <hip/hip_runtime.h>
#include <hip/hip_fp16.h>
#include <math.h>

// Problem constants (fixed by reference setup_inputs)
#define E_ 4
#define L_ 10
#define S_ 1024
#define F_ 256
#define T_ 1024
#define NROW (E_*L_*S_)     // 40960 rows of the input GEMM
#define KPAD2 384           // left pad of each padded W row (halfs), mult of 8
#define WROW 1920           // padded W row stride in halfs (384+1024+512)
#define TTW  864            // Toeplitz block width (a-dim), covers 2*K4max+96
#define RSTR 1032           // replica stride (floats): 8-bank skew per replica

// workspace layout (float indices). OUT aliases MT (MT dead after k2).
#define OFF_TT  64                       // f16 TT[64][864]
#define OFF_M   32768                    // fp32 MT[el][f][s], 40*256*1024 floats (= OUT alias)
#define OFF_WH  (32768 + (size_t)NROW * F_)        // f16 padded W planes
#define OFF_PT  (OFF_WH + (size_t)40 * F_ * WROW / 2)  // f16 PT[256][256]

typedef _Float16 half8 __attribute__((ext_vector_type(8)));
typedef float f32x4v __attribute__((ext_vector_type(4)));

__device__ __forceinline__ unsigned int encf(float x) {
  unsigned int b = __float_as_uint(x);
  return (b & 0x80000000u) ? ~b : (b | 0x80000000u);
}
__device__ __forceinline__ float decf(unsigned int u) {
  unsigned int b = (u & 0x80000000u) ? (u ^ 0x80000000u) : ~u;
  return __uint_as_float(b);
}

// K_pt: PT[c][k] = (f16)P[k][c]. Coalesced reads, scattered 2B writes (tiny).
__global__ __launch_bounds__(256) void k_pt(const float* __restrict__ P,
                                            _Float16* __restrict__ PT) {
  const int k = blockIdx.x;
  const int c = threadIdx.x;
  PT[(size_t)c * F_ + k] = (_Float16)P[(size_t)k * F_ + c];
}

// K0: m = matrix @ params via MFMA f16 hi/lo split; writes M TRANSPOSED:
// MT[el][f][s]. C-frag rows are consecutive s -> contiguous float4 stores.
// Fused global min/max.
__global__ __launch_bounds__(256) void k0_mfma(const float* __restrict__ A,
                                               const _Float16* __restrict__ PT,
                                               float* __restrict__ MT,
                                               unsigned int* __restrict__ slots) {
  __shared__ __align__(16) _Float16 Ahi[64][40];   // 5 KB, 80 B row stride
  __shared__ __align__(16) _Float16 Alo[64][40];   // 5 KB
  __shared__ __align__(16) _Float16 Bl[256][40];   // 20 KB
  const int tid = threadIdx.x;
  const int wave = tid >> 6, lane = tid & 63;
  const int nn = lane & 15, quad = lane >> 4;
  const int row0 = blockIdx.x * 64;                 // global s-row base
  const int el = blockIdx.x >> 4;
  const int s0 = (blockIdx.x & 15) * 64;            // s base within el
  f32x4v acc[4][4];
#pragma unroll
  for (int rt = 0; rt < 4; ++rt)
#pragma unroll
    for (int ct = 0; ct < 4; ++ct) acc[rt][ct] = (f32x4v){0.f, 0.f, 0.f, 0.f};
  for (int kc = 0; kc < 8; ++kc) {
    __syncthreads();
    {  // stage A chunk 64 rows x 32 k: fp32 -> f16 hi/lo
      const int r = tid >> 2, part = tid & 3;
      const float* src = A + (size_t)(row0 + r) * F_ + kc * 32 + part * 8;
      float4 v0 = ((const float4*)src)[0];
      float4 v1 = ((const float4*)src)[1];
      float vv[8] = {v0.x, v0.y, v0.z, v0.w, v1.x, v1.y, v1.z, v1.w};
      half8 hh, hl;
#pragma unroll
      for (int j = 0; j < 8; ++j) {
        _Float16 h = (_Float16)vv[j];
        hh[j] = h;
        hl[j] = (_Float16)(vv[j] - (float)h);
      }
      *(half8*)&Ahi[r][part * 8] = hh;
      *(half8*)&Alo[r][part * 8] = hl;
    }
    {  // stage B chunk: Bl[c][0..32) = PT[c][kc*32..+32)
      const int4* bs = (const int4*)(PT + (size_t)tid * F_ + kc * 32);
      int4 b0 = bs[0], b1 = bs[1], b2 = bs[2], b3 = bs[3];
      int4* bd = (int4*)&Bl[tid][0];
      bd[0] = b0; bd[1] = b1; bd[2] = b2; bd[3] = b3;
    }
    __syncthreads();
    half8 afh[4], afl[4], bf[4];
#pragma unroll
    for (int rt = 0; rt < 4; ++rt) {
      afh[rt] = *(const half8*)&Ahi[rt * 16 + nn][quad * 8];
      afl[rt] = *(const half8*)&Alo[rt * 16 + nn][quad * 8];
    }
#pragma unroll
    for (int ct = 0; ct < 4; ++ct)
      bf[ct] = *(const half8*)&Bl[wave * 64 + ct * 16 + nn][quad * 8];
#pragma unroll
    for (int rt = 0; rt < 4; ++rt)
#pragma unroll
      for (int ct = 0; ct < 4; ++ct) {
        acc[rt][ct] = __builtin_amdgcn_mfma_f32_16x16x32_f16(afh[rt], bf[ct], acc[rt][ct], 0, 0, 0);
        acc[rt][ct] = __builtin_amdgcn_mfma_f32_16x16x32_f16(afl[rt], bf[ct], acc[rt][ct], 0, 0, 0);
      }
  }
  // store MT[(el*F+col)*S + s] + fused min/max. C layout: s = quad*4+j, col = nn.
  float vmin = 3.4e38f, vmax = -3.4e38f;
#pragma unroll
  for (int rt = 0; rt < 4; ++rt)
#pragma unroll
    for (int ct = 0; ct < 4; ++ct) {
      f32x4v c = acc[rt][ct];
      const int col = wave * 64 + ct * 16 + nn;
      const int sl = s0 + rt * 16 + quad * 4;
      *(float4*)&MT[((size_t)el * F_ + col) * S_ + sl] =
          make_float4(c[0], c[1], c[2], c[3]);
      vmin = fminf(vmin, fminf(fminf(c[0], c[1]), fminf(c[2], c[3])));
      vmax = fmaxf(vmax, fmaxf(fmaxf(c[0], c[1]), fmaxf(c[2], c[3])));
    }
#pragma unroll
  for (int off = 32; off; off >>= 1) {
    vmin = fminf(vmin, __shfl_down(vmin, off));
    vmax = fmaxf(vmax, __shfl_down(vmax, off));
  }
  if (lane == 0) {
    atomicMin(&slots[0], encf(vmin));
    atomicMax(&slots[1], encf(vmax));
  }
}

// K1: grid constants only (1 block).
__global__ __launch_bounds__(64) void k1_setup(const unsigned int* __restrict__ slots,
                                               float* __restrict__ hdr,
                                               int* __restrict__ hdri) {
  if (threadIdx.x == 0) {
    const float left = decf(slots[0]);
    const float right = decf(slots[1]);
    const float dg = (right - left) / 1023.0f;    // linspace step (1024 pts)
    const float inv_dg = 1.0f / dg;
    const float delta = (right - left) / 1024.0f; // reference's delta
    const float divisor = 0.62665706865775006f;   // sqrt(2*pi)*0.25
    const float scale = delta * 0.5f / divisor;
    int kmax = (int)(2.39792f * inv_dg) + 1;      // exp(-8u^2)<1e-20 beyond
    if (kmax > 368) kmax = 368;
    const int K4 = (kmax + 8) & ~7;               // mult of 8, > kmax, <= 376
    hdr[0] = left; hdr[1] = dg; hdr[2] = inv_dg; hdr[3] = scale;
    hdri[4] = K4; hdri[5] = kmax;
  }
}

// K1b: Toeplitz block TT[b][ak] = G(b + K4 - ak), f16. One block per b row.
__global__ __launch_bounds__(256) void k1b_tt(const float* __restrict__ hdr,
                                              const int* __restrict__ hdri,
                                              __half* __restrict__ TT) {
  const int b = blockIdx.x;
  const float dg = hdr[1];
  const int K4 = hdri[4], kmax = hdri[5];
  for (int ak = threadIdx.x; ak < TTW; ak += 256) {
    int d = b + K4 - ak;
    int ad = d < 0 ? -d : d;
    float u = (float)d * dg;
    float v = (ad <= kmax) ? expf(-8.0f * u * u) : 0.0f;
    TT[(size_t)b * TTW + ak] = __float2half(v);
  }
}

// K2: linear binning with 4-way privatized, bank-skewed replica histograms.
// Block = (el, f-pair): 2 rows x 4 replicas x 1032 floats = 33 KB LDS.
// Replica = (tid>>4)&3 -> 16 lanes/replica per atomic instr (same-address
// collision pairs cut 4x); stride 1032 = 8-bank skew (replicas hit different
// banks for equal j). Merge pass is conflict-free b128 reads.
__global__ __launch_bounds__(256) void k2_bin(const float* __restrict__ MT,
                                              const float* __restrict__ hdr,
                                              __half* __restrict__ Wh) {
  __shared__ float wl[2][4][RSTR];   // 33 KB
  const int tid = threadIdx.x;
  const int el = blockIdx.x >> 7;
  const int fp = blockIdx.x & 127;   // f-pair
  {
    float4* z = (float4*)&wl[0][0][0];
    for (int i = tid; i < 2 * 4 * RSTR / 4; i += 256)
      z[i] = make_float4(0.f, 0.f, 0.f, 0.f);
  }
  __syncthreads();
  const float left = hdr[0];
  const float inv_dg = hdr[2];
  const int row = tid >> 7;          // 0..1
  const int u = tid & 127;           // sample chunk within row
  const int rep = (tid >> 4) & 3;    // replica
  const float* base = MT + ((size_t)el * F_ + fp * 2 + row) * S_ + u * 8;
  float4 v0 = ((const float4*)base)[0];
  float4 v1 = ((const float4*)base)[1];
  float vv[8] = {v0.x, v0.y, v0.z, v0.w, v1.x, v1.y, v1.z, v1.w};
#pragma unroll
  for (int c = 0; c < 8; ++c) {
    float p = (vv[c] - left) * inv_dg;
    int j = (int)p;
    if (j > 1022) j = 1022;
    float a = p - (float)j;
    atomicAdd(&wl[row][rep][j], 1.0f - a);
    atomicAdd(&wl[row][rep][j + 1], a);
  }
  __syncthreads();
  // merge 4 replicas, convert to f16, write 8 bins/thread.
  const int mrow = tid >> 7;
  const int b8 = (tid & 127) * 8;
  float4 s0 = *(const float4*)&wl[mrow][0][b8];
  float4 s1 = *(const float4*)&wl[mrow][0][b8 + 4];
#pragma unroll
  for (int rp = 1; rp < 4; ++rp) {
    float4 a = *(const float4*)&wl[mrow][rp][b8];
    float4 b = *(const float4*)&wl[mrow][rp][b8 + 4];
    s0.x += a.x; s0.y += a.y; s0.z += a.z; s0.w += a.w;
    s1.x += b.x; s1.y += b.y; s1.z += b.z; s1.w += b.w;
  }
  half8 h;
  h[0] = (_Float16)s0.x; h[1] = (_Float16)s0.y; h[2] = (_Float16)s0.z; h[3] = (_Float16)s0.w;
  h[4] = (_Float16)s1.x; h[5] = (_Float16)s1.y; h[6] = (_Float16)s1.z; h[7] = (_Float16)s1.w;
  _Float16* wrow = (_Float16*)Wh + ((size_t)el * F_ + fp * 2 + mrow) * WROW + KPAD2 + b8;
  *(half8*)wrow = h;
}

// K3: banded-Toeplitz GEMM via MFMA f32_16x16x32_f16.
// Block = (el, t-tile of 64): OUT[el][f=0..255][t0..t0+63] = W x TT.
// 4 waves; wave w owns f in [64w, 64w+64): 4x4 grid of 16x16 MFMA tiles.
__global__ __launch_bounds__(256) void k3_mfma(const _Float16* __restrict__ Wh,
                                               const _Float16* __restrict__ TT,
                                               const int* __restrict__ hdri,
                                               float* __restrict__ OUT) {
  __shared__ __align__(16) _Float16 Wl[256][40];  // 20 KB, row 80 B
  const int tid = threadIdx.x;
  const int wave = tid >> 6, lane = tid & 63;
  const int nn = lane & 15, quad = lane >> 4;
  const int el = blockIdx.x >> 4;
  const int t0 = (blockIdx.x & 15) << 6;
  const int K4 = hdri[4];
  const int nkc = (2 * K4 + 64 + 31) >> 5;
  const _Float16* Wp = Wh + (size_t)el * F_ * WROW + (KPAD2 - K4 + t0);
  f32x4v acc[4][4];
#pragma unroll
  for (int ft = 0; ft < 4; ++ft)
#pragma unroll
    for (int tn = 0; tn < 4; ++tn) acc[ft][tn] = (f32x4v){0.f, 0.f, 0.f, 0.f};
  for (int kc = 0; kc < nkc; ++kc) {
    __syncthreads();
    {
      const int4* s = (const int4*)(Wp + (size_t)tid * WROW + kc * 32);
      int4 v0 = s[0], v1 = s[1], v2 = s[2], v3 = s[3];
      int4* d = (int4*)&Wl[tid][0];
      d[0] = v0; d[1] = v1; d[2] = v2; d[3] = v3;
    }
    __syncthreads();
    half8 bf[4];
#pragma unroll
    for (int tn = 0; tn < 4; ++tn)
      bf[tn] = *(const half8*)(TT + (size_t)(tn * 16 + nn) * TTW + kc * 32 + quad * 8);
#pragma unroll
    for (int ft = 0; ft < 4; ++ft) {
      half8 af = *(const half8*)&Wl[wave * 64 + ft * 16 + nn][quad * 8];
#pragma unroll
      for (int tn = 0; tn < 4; ++tn)
        acc[ft][tn] = __builtin_amdgcn_mfma_f32_16x16x32_f16(af, bf[tn], acc[ft][tn], 0, 0, 0);
    }
  }
  float* Ob = OUT + (size_t)el * F_ * T_ + t0;
#pragma unroll
  for (int ft = 0; ft < 4; ++ft)
#pragma unroll
    for (int tn = 0; tn < 4; ++tn) {
      f32x4v c = acc[ft][tn];
      const int fb = wave * 64 + ft * 16 + quad * 4;
      const int tc = tn * 16 + nn;
      Ob[(size_t)(fb + 0) * T_ + tc] = c[0];
      Ob[(size_t)(fb + 1) * T_ + tc] = c[1];
      Ob[(size_t)(fb + 2) * T_ + tc] = c[2];
      Ob[(size_t)(fb + 3) * T_ + tc] = c[3];
    }
}

// K4: epilogue. Block = (l,f); thread = 4 t. red=(ksum-(S-dl)et)/dl, 6 pair
// |diff| sums over t, reduce, train/test max, write.
__global__ __launch_bounds__(256) void k4_epi(const float* __restrict__ OUT,
                                              const float* __restrict__ hdr,
                                              const float* __restrict__ dl,
                                              float* __restrict__ out) {
  __shared__ float rs[4][6];
  const int tid = threadIdx.x;
  const int l = blockIdx.x >> 8;
  const int f = blockIdx.x & 255;
  const float left = hdr[0], dg = hdr[1], scale = hdr[3];
  const int t = 4 * tid;
  float etv[4];
#pragma unroll
  for (int d = 0; d < 4; ++d) {
    float x = left + (float)(t + d) * dg;
    etv[d] = expf(-8.0f * x * x);
  }
  float red[E_][4];
#pragma unroll
  for (int e = 0; e < E_; ++e) {
    float4 ks = *(const float4*)(OUT + (((size_t)(e * L_ + l)) * F_ + f) * T_ + t);
    const float dlv = dl[e * L_ + l];
    const float zc = (float)S_ - dlv;
    const float idl = 1.0f / dlv;
    red[e][0] = (ks.x - zc * etv[0]) * idl;
    red[e][1] = (ks.y - zc * etv[1]) * idl;
    red[e][2] = (ks.z - zc * etv[2]) * idl;
    red[e][3] = (ks.w - zc * etv[3]) * idl;
  }
  float D[6];
  const int pa[6] = {0, 0, 0, 1, 1, 2};
  const int pb[6] = {1, 2, 3, 2, 3, 3};
#pragma unroll
  for (int p = 0; p < 6; ++p) {
    float s = 0.f;
#pragma unroll
    for (int d = 0; d < 4; ++d) s += fabsf(red[pa[p]][d] - red[pb[p]][d]);
    D[p] = s;
  }
#pragma unroll
  for (int off = 32; off; off >>= 1)
#pragma unroll
    for (int p = 0; p < 6; ++p) D[p] += __shfl_down(D[p], off);
  if ((tid & 63) == 0) {
#pragma unroll
    for (int p = 0; p < 6; ++p) rs[tid >> 6][p] = D[p];
  }
  __syncthreads();
  if (tid == 0) {
    float Tp[6];
#pragma unroll
    for (int p = 0; p < 6; ++p)
      Tp[p] = (rs[0][p] + rs[1][p] + rs[2][p] + rs[3][p]) * scale;
    float test = Tp[0];
#pragma unroll
    for (int p = 1; p < 6; ++p) test = fmaxf(test, Tp[p]);
    float train = fmaxf(fmaxf(Tp[1], Tp[2]), Tp[5]);
    out[l * F_ + f] = train;                 // train_results
    out[L_ * F_ + l * F_ + f] = test;        // test_results
  }
}

extern "C" void kernel_launch(void* const* d_in, const int* in_sizes, int n_in,
                              void* d_out, int out_size, void* d_ws, size_t ws_size,
                              hipStream_t stream) {
  const float* A  = (const float*)d_in[0];   // matrix (4,10,1024,256)
  const float* dl = (const float*)d_in[1];   // data_len (4,10)
  const float* P  = (const float*)d_in[2];   // params (256,256)
  float* out = (float*)d_out;
  float* ws = (float*)d_ws;
  float* hdr = ws;
  int* hdri = (int*)d_ws;
  unsigned int* slots = (unsigned int*)(ws + 16);
  __half* TTh = (__half*)(ws + OFF_TT);
  float* MT  = ws + OFF_M;        // fp32 GEMM result, f-major (dead after k2)
  float* OUT = ws + OFF_M;        // OUT aliases MT
  __half* Wh = (__half*)(ws + OFF_WH);
  _Float16* PT = (_Float16*)(ws + OFF_PT);

  // Defensive determinism: the harness poisons d_ws with 0xAA before every
  // timed launch. 0xAA-poison is ~0 in fp32 (-3e-13) but -0.052 as f16 — any
  // read-before-write hole in an f16 region makes replays diverge from the
  // first call (seen in round 8: post-timing absmax 1.37e-2). Zero ALL f16
  // regions up front so the output is a pure function of d_in.
  (void)hipMemsetAsync(Wh, 0, (size_t)40 * F_ * WROW * 2, stream);   // ~37.5 MB
  (void)hipMemsetAsync(TTh, 0, (size_t)64 * TTW * 2, stream);
  (void)hipMemsetAsync(PT, 0, (size_t)F_ * F_ * 2, stream);
  (void)hipMemsetAsync(slots, 0xFF, 4, stream);      // min slot neutral
  (void)hipMemsetAsync(slots + 1, 0x00, 4, stream);  // max slot neutral

  k_pt<<<F_, 256, 0, stream>>>(P, PT);
  k0_mfma<<<NROW / 64, 256, 0, stream>>>(A, PT, MT, slots);
  k1_setup<<<1, 64, 0, stream>>>(slots, hdr, hdri);
  k1b_tt<<<64, 256, 0, stream>>>(hdr, hdri, TTh);
  k2_bin<<<(E_ * L_) * (F_ / 2), 256, 0, stream>>>(MT, hdr, Wh);
  k3_mfma<<<(E_ * L_) * 16, 256, 0, stream>>>((const _Float16*)Wh, (const _Float16*)TTh,
                                              hdri, OUT);
  k4_epi<<<L_ * F_, 256, 0, stream>>>(OUT, hdr, dl, out);
}

// Round 11
// 287.137 us; speedup vs baseline: 1.2192x; 1.2192x over previous
//
#include <hip/hip_runtime.h>
#include <hip/hip_fp16.h>
#include <math.h>

// Problem constants (fixed by reference setup_inputs)
#define E_ 4
#define L_ 10
#define S_ 1024
#define F_ 256
#define T_ 1024
#define NROW (E_*L_*S_)     // 40960 rows of the input GEMM
#define NH   64             // Fourier harmonics (cos+sin each)
#define CSW  288            // padded CS/BT row width in halves (258 live + pad)

// workspace layout (float indices). OUT aliases MT (MT dead after kF).
#define OFF_M   32768                          // fp32 MT[el][f][s] (= OUT alias)
#define OFF_CS  (32768 + (size_t)NROW * F_)    // f16 CS[el][f][288] hi/lo pairs
#define OFF_BT  (OFF_CS + (size_t)40 * F_ * CSW / 2)   // f16 BT[t][288]
#define OFF_PT  (OFF_BT + (size_t)T_ * CSW / 2)        // f16 PT[256][256]

typedef _Float16 half8 __attribute__((ext_vector_type(8)));
typedef float f32x4v __attribute__((ext_vector_type(4)));

__device__ __forceinline__ unsigned int encf(float x) {
  unsigned int b = __float_as_uint(x);
  return (b & 0x80000000u) ? ~b : (b | 0x80000000u);
}
__device__ __forceinline__ float decf(unsigned int u) {
  unsigned int b = (u & 0x80000000u) ? (u ^ 0x80000000u) : ~u;
  return __uint_as_float(b);
}
__device__ __forceinline__ void put_hl(_Float16* p, float v) {
  _Float16 h = (_Float16)v;
  _Float16 l = (_Float16)(v - (float)h);
  p[0] = h; p[1] = l;
}

// K_pt: PT[c][k] = (f16)P[k][c].
__global__ __launch_bounds__(256) void k_pt(const float* __restrict__ P,
                                            _Float16* __restrict__ PT) {
  const int k = blockIdx.x;
  const int c = threadIdx.x;
  PT[(size_t)c * F_ + k] = (_Float16)P[(size_t)k * F_ + c];
}

// K0: m = matrix @ params via MFMA f16 hi/lo split; writes M TRANSPOSED:
// MT[el][f][s]. Fused global min/max. (validated rounds 6-10)
__global__ __launch_bounds__(256) void k0_mfma(const float* __restrict__ A,
                                               const _Float16* __restrict__ PT,
                                               float* __restrict__ MT,
                                               unsigned int* __restrict__ slots) {
  __shared__ __align__(16) _Float16 Ahi[64][40];
  __shared__ __align__(16) _Float16 Alo[64][40];
  __shared__ __align__(16) _Float16 Bl[256][40];
  const int tid = threadIdx.x;
  const int wave = tid >> 6, lane = tid & 63;
  const int nn = lane & 15, quad = lane >> 4;
  const int row0 = blockIdx.x * 64;
  const int el = blockIdx.x >> 4;
  const int s0 = (blockIdx.x & 15) * 64;
  f32x4v acc[4][4];
#pragma unroll
  for (int rt = 0; rt < 4; ++rt)
#pragma unroll
    for (int ct = 0; ct < 4; ++ct) acc[rt][ct] = (f32x4v){0.f, 0.f, 0.f, 0.f};
  for (int kc = 0; kc < 8; ++kc) {
    __syncthreads();
    {
      const int r = tid >> 2, part = tid & 3;
      const float* src = A + (size_t)(row0 + r) * F_ + kc * 32 + part * 8;
      float4 v0 = ((const float4*)src)[0];
      float4 v1 = ((const float4*)src)[1];
      float vv[8] = {v0.x, v0.y, v0.z, v0.w, v1.x, v1.y, v1.z, v1.w};
      half8 hh, hl;
#pragma unroll
      for (int j = 0; j < 8; ++j) {
        _Float16 h = (_Float16)vv[j];
        hh[j] = h;
        hl[j] = (_Float16)(vv[j] - (float)h);
      }
      *(half8*)&Ahi[r][part * 8] = hh;
      *(half8*)&Alo[r][part * 8] = hl;
    }
    {
      const int4* bs = (const int4*)(PT + (size_t)tid * F_ + kc * 32);
      int4 b0 = bs[0], b1 = bs[1], b2 = bs[2], b3 = bs[3];
      int4* bd = (int4*)&Bl[tid][0];
      bd[0] = b0; bd[1] = b1; bd[2] = b2; bd[3] = b3;
    }
    __syncthreads();
    half8 afh[4], afl[4], bf[4];
#pragma unroll
    for (int rt = 0; rt < 4; ++rt) {
      afh[rt] = *(const half8*)&Ahi[rt * 16 + nn][quad * 8];
      afl[rt] = *(const half8*)&Alo[rt * 16 + nn][quad * 8];
    }
#pragma unroll
    for (int ct = 0; ct < 4; ++ct)
      bf[ct] = *(const half8*)&Bl[wave * 64 + ct * 16 + nn][quad * 8];
#pragma unroll
    for (int rt = 0; rt < 4; ++rt)
#pragma unroll
      for (int ct = 0; ct < 4; ++ct) {
        acc[rt][ct] = __builtin_amdgcn_mfma_f32_16x16x32_f16(afh[rt], bf[ct], acc[rt][ct], 0, 0, 0);
        acc[rt][ct] = __builtin_amdgcn_mfma_f32_16x16x32_f16(afl[rt], bf[ct], acc[rt][ct], 0, 0, 0);
      }
  }
  float vmin = 3.4e38f, vmax = -3.4e38f;
#pragma unroll
  for (int rt = 0; rt < 4; ++rt)
#pragma unroll
    for (int ct = 0; ct < 4; ++ct) {
      f32x4v c = acc[rt][ct];
      const int col = wave * 64 + ct * 16 + nn;
      const int sl = s0 + rt * 16 + quad * 4;
      *(float4*)&MT[((size_t)el * F_ + col) * S_ + sl] =
          make_float4(c[0], c[1], c[2], c[3]);
      vmin = fminf(vmin, fminf(fminf(c[0], c[1]), fminf(c[2], c[3])));
      vmax = fmaxf(vmax, fmaxf(fmaxf(c[0], c[1]), fmaxf(c[2], c[3])));
    }
#pragma unroll
  for (int off = 32; off; off >>= 1) {
    vmin = fminf(vmin, __shfl_down(vmin, off));
    vmax = fmaxf(vmax, __shfl_down(vmax, off));
  }
  if (lane == 0) {
    atomicMin(&slots[0], encf(vmin));
    atomicMax(&slots[1], encf(vmax));
  }
}

// K1: grid + Fourier constants.
__global__ __launch_bounds__(64) void k1_setup(const unsigned int* __restrict__ slots,
                                               float* __restrict__ hdr) {
  if (threadIdx.x == 0) {
    const float left = decf(slots[0]);
    const float right = decf(slots[1]);
    const float dg = (right - left) / 1023.0f;
    const float delta = (right - left) / 1024.0f;
    const float divisor = 0.62665706865775006f;   // sqrt(2*pi)*0.25
    const float scale = delta * 0.5f / divisor;
    const float Pp = (right - left) + 5.0f;       // period (alias gap > 2.4)
    const float sqpi8 = 0.62665706865775006f;     // sqrt(pi/8)
    hdr[0] = left; hdr[1] = dg; hdr[2] = 0.f; hdr[3] = scale;
    hdr[4] = 6.2831853071795864f / Pp;            // omega1
    hdr[5] = 2.0f * sqpi8 / Pp;                   // a_k scale
    hdr[6] = sqpi8 / Pp;                          // a_0
  }
}

// KB: basis matrix BT[t][j], j=2*kidx(+1): kidx 0=DC, 1..64=a_k cos(w_k x_t),
// 65..128=a_k sin. Both hi/lo slots carry the same value (CS carries hi/lo).
__global__ __launch_bounds__(320) void kB(const float* __restrict__ hdr,
                                          _Float16* __restrict__ BT) {
  const int t = blockIdx.x;
  const int j = threadIdx.x;
  if (j >= CSW) return;
  const float left = hdr[0], dg = hdr[1];
  const float w1 = hdr[4], asc = hdr[5], a0 = hdr[6];
  const float x = left + (float)t * dg;
  float v = 0.f;
  const int kidx = j >> 1;
  if (j < 258) {
    if (kidx == 0) v = a0;
    else if (kidx <= NH) {
      float wk = w1 * (float)kidx;
      v = asc * expf(-wk * wk * 0.03125f) * __cosf(wk * x);
    } else {
      float wk = w1 * (float)(kidx - NH);
      v = asc * expf(-wk * wk * 0.03125f) * __sinf(wk * x);
    }
  }
  BT[(size_t)t * CSW + j] = (_Float16)v;
}

// KF: Fourier sums C_k(f)=sum_s cos(w_k m), S_k likewise — replaces the LDS
// atomic histogram (21M lane-atomics at ~3.3cyc/lane were the k2 wall).
// Block = (el, fgroup of 8); thread = (f, 32-sample slice). Chebyshev 3-term
// recurrence over k, register accumulators, two 32-harmonic phases (VGPR cap),
// width-32 shuffle reduction. No atomics, no LDS.
__global__ __launch_bounds__(256) void kF(const float* __restrict__ MT,
                                          const float* __restrict__ hdr,
                                          _Float16* __restrict__ CS) {
  const int tid = threadIdx.x;
  const int floc = tid >> 5, slice = tid & 31;
  const int el = blockIdx.x >> 5;
  const int fg = blockIdx.x & 31;
  const int f = fg * 8 + floc;
  const float w1 = hdr[4];
  const float* src = MT + ((size_t)el * F_ + f) * S_ + slice * 32;
  _Float16* csrow = CS + ((size_t)el * F_ + f) * CSW;
  const bool lead = (slice == 0);
  // phase 1: harmonics 1..32
  {
    float aC[32], aS[32];
#pragma unroll
    for (int k = 0; k < 32; ++k) { aC[k] = 0.f; aS[k] = 0.f; }
    for (int it = 0; it < 8; ++it) {
      float4 v4 = ((const float4*)src)[it];
      float mv[4] = {v4.x, v4.y, v4.z, v4.w};
#pragma unroll
      for (int c = 0; c < 4; ++c) {
        float al = w1 * mv[c];
        float s1, c1;
        __sincosf(al, &s1, &c1);
        const float tc = 2.f * c1;
        float cp = c1, sp = s1, cpp = 1.f, spp = 0.f;
        aC[0] += c1; aS[0] += s1;
#pragma unroll
        for (int k = 1; k < 32; ++k) {
          float cn = tc * cp - cpp;
          float sn = tc * sp - spp;
          aC[k] += cn; aS[k] += sn;
          cpp = cp; cp = cn; spp = sp; sp = sn;
        }
      }
    }
#pragma unroll
    for (int off = 16; off; off >>= 1)
#pragma unroll
      for (int k = 0; k < 32; ++k) {
        aC[k] += __shfl_down(aC[k], off, 32);
        aS[k] += __shfl_down(aS[k], off, 32);
      }
    if (lead) {
      csrow[0] = (_Float16)1024.f;   // DC: C_0 = S count (exact)
      csrow[1] = (_Float16)0.f;
#pragma unroll
      for (int k = 0; k < 32; ++k) {
        put_hl(csrow + 2 * (1 + k), aC[k]);     // cos harmonics 1..32
        put_hl(csrow + 2 * (65 + k), aS[k]);    // sin harmonics 1..32
      }
    }
  }
  // phase 2: harmonics 33..64
  {
    float aC[32], aS[32];
#pragma unroll
    for (int k = 0; k < 32; ++k) { aC[k] = 0.f; aS[k] = 0.f; }
    for (int it = 0; it < 8; ++it) {
      float4 v4 = ((const float4*)src)[it];
      float mv[4] = {v4.x, v4.y, v4.z, v4.w};
#pragma unroll
      for (int c = 0; c < 4; ++c) {
        float al = w1 * mv[c];
        float s1, c1, s32v, c32v;
        __sincosf(al, &s1, &c1);
        __sincosf(32.f * al, &s32v, &c32v);
        const float tc = 2.f * c1;
        float c33 = c32v * c1 - s32v * s1;
        float s33 = s32v * c1 + c32v * s1;
        float cp = c33, cpp = c32v, sp = s33, spp = s32v;
        aC[0] += c33; aS[0] += s33;
#pragma unroll
        for (int k = 1; k < 32; ++k) {
          float cn = tc * cp - cpp;
          float sn = tc * sp - spp;
          aC[k] += cn; aS[k] += sn;
          cpp = cp; cp = cn; spp = sp; sp = sn;
        }
      }
    }
#pragma unroll
    for (int off = 16; off; off >>= 1)
#pragma unroll
      for (int k = 0; k < 32; ++k) {
        aC[k] += __shfl_down(aC[k], off, 32);
        aS[k] += __shfl_down(aS[k], off, 32);
      }
    if (lead) {
#pragma unroll
      for (int k = 0; k < 32; ++k) {
        put_hl(csrow + 2 * (33 + k), aC[k]);    // cos harmonics 33..64
        put_hl(csrow + 2 * (97 + k), aS[k]);    // sin harmonics 33..64
      }
    }
  }
}

// KR: reconstruction GEMM ksum = CS x BT^T via MFMA (9 K-chunks of 32).
// Block = (el, t-tile of 64); wave w owns f in [64w,64w+64): 4x4 16x16 tiles.
__global__ __launch_bounds__(256) void kR(const _Float16* __restrict__ CS,
                                          const _Float16* __restrict__ BT,
                                          float* __restrict__ OUT) {
  __shared__ __align__(16) _Float16 Wl[256][40];
  const int tid = threadIdx.x;
  const int wave = tid >> 6, lane = tid & 63;
  const int nn = lane & 15, quad = lane >> 4;
  const int el = blockIdx.x >> 4;
  const int t0 = (blockIdx.x & 15) << 6;
  const _Float16* Ap = CS + (size_t)el * F_ * CSW;
  f32x4v acc[4][4];
#pragma unroll
  for (int ft = 0; ft < 4; ++ft)
#pragma unroll
    for (int tn = 0; tn < 4; ++tn) acc[ft][tn] = (f32x4v){0.f, 0.f, 0.f, 0.f};
  for (int kc = 0; kc < CSW / 32; ++kc) {
    __syncthreads();
    {
      const int4* s = (const int4*)(Ap + (size_t)tid * CSW + kc * 32);
      int4 v0 = s[0], v1 = s[1], v2 = s[2], v3 = s[3];
      int4* d = (int4*)&Wl[tid][0];
      d[0] = v0; d[1] = v1; d[2] = v2; d[3] = v3;
    }
    __syncthreads();
    half8 bf[4];
#pragma unroll
    for (int tn = 0; tn < 4; ++tn)
      bf[tn] = *(const half8*)(BT + (size_t)(t0 + tn * 16 + nn) * CSW + kc * 32 + quad * 8);
#pragma unroll
    for (int ft = 0; ft < 4; ++ft) {
      half8 af = *(const half8*)&Wl[wave * 64 + ft * 16 + nn][quad * 8];
#pragma unroll
      for (int tn = 0; tn < 4; ++tn)
        acc[ft][tn] = __builtin_amdgcn_mfma_f32_16x16x32_f16(af, bf[tn], acc[ft][tn], 0, 0, 0);
    }
  }
  float* Ob = OUT + (size_t)el * F_ * T_ + t0;
#pragma unroll
  for (int ft = 0; ft < 4; ++ft)
#pragma unroll
    for (int tn = 0; tn < 4; ++tn) {
      f32x4v c = acc[ft][tn];
      const int fb = wave * 64 + ft * 16 + quad * 4;
      const int tc = tn * 16 + nn;
      Ob[(size_t)(fb + 0) * T_ + tc] = c[0];
      Ob[(size_t)(fb + 1) * T_ + tc] = c[1];
      Ob[(size_t)(fb + 2) * T_ + tc] = c[2];
      Ob[(size_t)(fb + 3) * T_ + tc] = c[3];
    }
}

// K4: epilogue (unchanged, validated).
__global__ __launch_bounds__(256) void k4_epi(const float* __restrict__ OUT,
                                              const float* __restrict__ hdr,
                                              const float* __restrict__ dl,
                                              float* __restrict__ out) {
  __shared__ float rs[4][6];
  const int tid = threadIdx.x;
  const int l = blockIdx.x >> 8;
  const int f = blockIdx.x & 255;
  const float left = hdr[0], dg = hdr[1], scale = hdr[3];
  const int t = 4 * tid;
  float etv[4];
#pragma unroll
  for (int d = 0; d < 4; ++d) {
    float x = left + (float)(t + d) * dg;
    etv[d] = expf(-8.0f * x * x);
  }
  float red[E_][4];
#pragma unroll
  for (int e = 0; e < E_; ++e) {
    float4 ks = *(const float4*)(OUT + (((size_t)(e * L_ + l)) * F_ + f) * T_ + t);
    const float dlv = dl[e * L_ + l];
    const float zc = (float)S_ - dlv;
    const float idl = 1.0f / dlv;
    red[e][0] = (ks.x - zc * etv[0]) * idl;
    red[e][1] = (ks.y - zc * etv[1]) * idl;
    red[e][2] = (ks.z - zc * etv[2]) * idl;
    red[e][3] = (ks.w - zc * etv[3]) * idl;
  }
  float D[6];
  const int pa[6] = {0, 0, 0, 1, 1, 2};
  const int pb[6] = {1, 2, 3, 2, 3, 3};
#pragma unroll
  for (int p = 0; p < 6; ++p) {
    float s = 0.f;
#pragma unroll
    for (int d = 0; d < 4; ++d) s += fabsf(red[pa[p]][d] - red[pb[p]][d]);
    D[p] = s;
  }
#pragma unroll
  for (int off = 32; off; off >>= 1)
#pragma unroll
    for (int p = 0; p < 6; ++p) D[p] += __shfl_down(D[p], off);
  if ((tid & 63) == 0) {
#pragma unroll
    for (int p = 0; p < 6; ++p) rs[tid >> 6][p] = D[p];
  }
  __syncthreads();
  if (tid == 0) {
    float Tp[6];
#pragma unroll
    for (int p = 0; p < 6; ++p)
      Tp[p] = (rs[0][p] + rs[1][p] + rs[2][p] + rs[3][p]) * scale;
    float test = Tp[0];
#pragma unroll
    for (int p = 1; p < 6; ++p) test = fmaxf(test, Tp[p]);
    float train = fmaxf(fmaxf(Tp[1], Tp[2]), Tp[5]);
    out[l * F_ + f] = train;
    out[L_ * F_ + l * F_ + f] = test;
  }
}

extern "C" void kernel_launch(void* const* d_in, const int* in_sizes, int n_in,
                              void* d_out, int out_size, void* d_ws, size_t ws_size,
                              hipStream_t stream) {
  const float* A  = (const float*)d_in[0];   // matrix (4,10,1024,256)
  const float* dl = (const float*)d_in[1];   // data_len (4,10)
  const float* P  = (const float*)d_in[2];   // params (256,256)
  float* out = (float*)d_out;
  float* ws = (float*)d_ws;
  float* hdr = ws;
  unsigned int* slots = (unsigned int*)(ws + 16);
  float* MT  = ws + OFF_M;                   // fp32 GEMM result (dead after kF)
  float* OUT = ws + OFF_M;                   // OUT aliases MT
  _Float16* CS = (_Float16*)(ws + OFF_CS);
  _Float16* BT = (_Float16*)(ws + OFF_BT);
  _Float16* PT = (_Float16*)(ws + OFF_PT);

  // Determinism under 0xAA ws-poison: zero all f16 regions (pads included).
  (void)hipMemsetAsync(CS, 0, (size_t)40 * F_ * CSW * 2, stream);   // 5.9 MB
  (void)hipMemsetAsync(BT, 0, (size_t)T_ * CSW * 2, stream);
  (void)hipMemsetAsync(PT, 0, (size_t)F_ * F_ * 2, stream);
  (void)hipMemsetAsync(slots, 0xFF, 4, stream);      // min slot neutral
  (void)hipMemsetAsync(slots + 1, 0x00, 4, stream);  // max slot neutral

  k_pt<<<F_, 256, 0, stream>>>(P, PT);
  k0_mfma<<<NROW / 64, 256, 0, stream>>>(A, PT, MT, slots);
  k1_setup<<<1, 64, 0, stream>>>(slots, hdr);
  kB<<<T_, 320, 0, stream>>>(hdr, BT);
  kF<<<(E_ * L_) * 32, 256, 0, stream>>>(MT, hdr, CS);
  kR<<<(E_ * L_) * 16, 256, 0, stream>>>(CS, BT, OUT);
  k4_epi<<<L_ * F_, 256, 0, stream>>>(OUT, hdr, dl, out);
}

// Round 12
// 258.526 us; speedup vs baseline: 1.3541x; 1.1107x over previous
//
#include <hip/hip_runtime.h>
#include <hip/hip_fp16.h>
#include <math.h>

// Problem constants (fixed by reference setup_inputs)
#define E_ 4
#define L_ 10
#define S_ 1024
#define F_ 256
#define T_ 1024
#define NROW (E_*L_*S_)     // 40960 rows of the input GEMM
#define NH   48             // Fourier harmonics (cos+sin each); tail e^-11.1
#define CSW  224            // padded CS/BT row width in halves (194 live + pad)

// workspace layout (float indices). OUT aliases MT (MT dead after kF).
#define OFF_M   32768                          // fp32 MT[el][f][s] (= OUT alias)
#define OFF_CS  (32768 + (size_t)NROW * F_)    // f16 CS[el][f][CSW] hi/lo pairs
#define OFF_BT  (OFF_CS + (size_t)40 * F_ * CSW / 2)   // f16 BT[t][CSW]
#define OFF_PT  (OFF_BT + (size_t)T_ * CSW / 2)        // f16 PT[256][256]

typedef _Float16 half8 __attribute__((ext_vector_type(8)));
typedef float f32x4v __attribute__((ext_vector_type(4)));

__device__ __forceinline__ unsigned int encf(float x) {
  unsigned int b = __float_as_uint(x);
  return (b & 0x80000000u) ? ~b : (b | 0x80000000u);
}
__device__ __forceinline__ float decf(unsigned int u) {
  unsigned int b = (u & 0x80000000u) ? (u ^ 0x80000000u) : ~u;
  return __uint_as_float(b);
}
__device__ __forceinline__ void put_hl(_Float16* p, float v) {
  _Float16 h = (_Float16)v;
  _Float16 l = (_Float16)(v - (float)h);
  p[0] = h; p[1] = l;
}

// K_pt: PT[c][k] = (f16)P[k][c].
__global__ __launch_bounds__(256) void k_pt(const float* __restrict__ P,
                                            _Float16* __restrict__ PT) {
  const int k = blockIdx.x;
  const int c = threadIdx.x;
  PT[(size_t)c * F_ + k] = (_Float16)P[(size_t)k * F_ + c];
}

// K0: m = matrix @ params via MFMA f16 hi/lo split; writes M TRANSPOSED:
// MT[el][f][s]. Fused global min/max. (validated rounds 6-11)
__global__ __launch_bounds__(256) void k0_mfma(const float* __restrict__ A,
                                               const _Float16* __restrict__ PT,
                                               float* __restrict__ MT,
                                               unsigned int* __restrict__ slots) {
  __shared__ __align__(16) _Float16 Ahi[64][40];
  __shared__ __align__(16) _Float16 Alo[64][40];
  __shared__ __align__(16) _Float16 Bl[256][40];
  const int tid = threadIdx.x;
  const int wave = tid >> 6, lane = tid & 63;
  const int nn = lane & 15, quad = lane >> 4;
  const int row0 = blockIdx.x * 64;
  const int el = blockIdx.x >> 4;
  const int s0 = (blockIdx.x & 15) * 64;
  f32x4v acc[4][4];
#pragma unroll
  for (int rt = 0; rt < 4; ++rt)
#pragma unroll
    for (int ct = 0; ct < 4; ++ct) acc[rt][ct] = (f32x4v){0.f, 0.f, 0.f, 0.f};
  for (int kc = 0; kc < 8; ++kc) {
    __syncthreads();
    {
      const int r = tid >> 2, part = tid & 3;
      const float* src = A + (size_t)(row0 + r) * F_ + kc * 32 + part * 8;
      float4 v0 = ((const float4*)src)[0];
      float4 v1 = ((const float4*)src)[1];
      float vv[8] = {v0.x, v0.y, v0.z, v0.w, v1.x, v1.y, v1.z, v1.w};
      half8 hh, hl;
#pragma unroll
      for (int j = 0; j < 8; ++j) {
        _Float16 h = (_Float16)vv[j];
        hh[j] = h;
        hl[j] = (_Float16)(vv[j] - (float)h);
      }
      *(half8*)&Ahi[r][part * 8] = hh;
      *(half8*)&Alo[r][part * 8] = hl;
    }
    {
      const int4* bs = (const int4*)(PT + (size_t)tid * F_ + kc * 32);
      int4 b0 = bs[0], b1 = bs[1], b2 = bs[2], b3 = bs[3];
      int4* bd = (int4*)&Bl[tid][0];
      bd[0] = b0; bd[1] = b1; bd[2] = b2; bd[3] = b3;
    }
    __syncthreads();
    half8 afh[4], afl[4], bf[4];
#pragma unroll
    for (int rt = 0; rt < 4; ++rt) {
      afh[rt] = *(const half8*)&Ahi[rt * 16 + nn][quad * 8];
      afl[rt] = *(const half8*)&Alo[rt * 16 + nn][quad * 8];
    }
#pragma unroll
    for (int ct = 0; ct < 4; ++ct)
      bf[ct] = *(const half8*)&Bl[wave * 64 + ct * 16 + nn][quad * 8];
#pragma unroll
    for (int rt = 0; rt < 4; ++rt)
#pragma unroll
      for (int ct = 0; ct < 4; ++ct) {
        acc[rt][ct] = __builtin_amdgcn_mfma_f32_16x16x32_f16(afh[rt], bf[ct], acc[rt][ct], 0, 0, 0);
        acc[rt][ct] = __builtin_amdgcn_mfma_f32_16x16x32_f16(afl[rt], bf[ct], acc[rt][ct], 0, 0, 0);
      }
  }
  float vmin = 3.4e38f, vmax = -3.4e38f;
#pragma unroll
  for (int rt = 0; rt < 4; ++rt)
#pragma unroll
    for (int ct = 0; ct < 4; ++ct) {
      f32x4v c = acc[rt][ct];
      const int col = wave * 64 + ct * 16 + nn;
      const int sl = s0 + rt * 16 + quad * 4;
      *(float4*)&MT[((size_t)el * F_ + col) * S_ + sl] =
          make_float4(c[0], c[1], c[2], c[3]);
      vmin = fminf(vmin, fminf(fminf(c[0], c[1]), fminf(c[2], c[3])));
      vmax = fmaxf(vmax, fmaxf(fmaxf(c[0], c[1]), fmaxf(c[2], c[3])));
    }
#pragma unroll
  for (int off = 32; off; off >>= 1) {
    vmin = fminf(vmin, __shfl_down(vmin, off));
    vmax = fmaxf(vmax, __shfl_down(vmax, off));
  }
  if (lane == 0) {
    atomicMin(&slots[0], encf(vmin));
    atomicMax(&slots[1], encf(vmax));
  }
}

// K1: grid + Fourier constants.
__global__ __launch_bounds__(64) void k1_setup(const unsigned int* __restrict__ slots,
                                               float* __restrict__ hdr) {
  if (threadIdx.x == 0) {
    const float left = decf(slots[0]);
    const float right = decf(slots[1]);
    const float dg = (right - left) / 1023.0f;
    const float delta = (right - left) / 1024.0f;
    const float divisor = 0.62665706865775006f;   // sqrt(2*pi)*0.25
    const float scale = delta * 0.5f / divisor;
    const float Pp = (right - left) + 5.0f;       // period (alias gap > 2.4)
    const float sqpi8 = 0.62665706865775006f;     // sqrt(pi/8)
    hdr[0] = left; hdr[1] = dg; hdr[2] = 0.f; hdr[3] = scale;
    hdr[4] = 6.2831853071795864f / Pp;            // omega1
    hdr[5] = 2.0f * sqpi8 / Pp;                   // a_k scale
    hdr[6] = sqpi8 / Pp;                          // a_0
  }
}

// KB: basis matrix BT[t][j], j=2*kidx(+1): kidx 0=DC, 1..48=a_k cos(w_k x_t),
// 49..96=a_k sin. Both hi/lo slots carry the same value (CS carries hi/lo).
__global__ __launch_bounds__(256) void kB(const float* __restrict__ hdr,
                                          _Float16* __restrict__ BT) {
  const int t = blockIdx.x;
  const int j = threadIdx.x;
  if (j >= CSW) return;
  const float left = hdr[0], dg = hdr[1];
  const float w1 = hdr[4], asc = hdr[5], a0 = hdr[6];
  const float x = left + (float)t * dg;
  float v = 0.f;
  const int kidx = j >> 1;
  if (j < 2 * (2 * NH + 1)) {
    if (kidx == 0) v = a0;
    else if (kidx <= NH) {
      float wk = w1 * (float)kidx;
      v = asc * expf(-wk * wk * 0.03125f) * __cosf(wk * x);
    } else {
      float wk = w1 * (float)(kidx - NH);
      v = asc * expf(-wk * wk * 0.03125f) * __sinf(wk * x);
    }
  }
  BT[(size_t)t * CSW + j] = (_Float16)v;
}

// KF: Fourier sums C_k(f)=sum_s cos(w_k m), S_k likewise. Single pass,
// 48 harmonics, 96 register accumulators, Chebyshev 3-term recurrence,
// one sincos per sample, width-32 shuffle reduction. No atomics, no LDS.
__global__ __launch_bounds__(256) void kF(const float* __restrict__ MT,
                                          const float* __restrict__ hdr,
                                          _Float16* __restrict__ CS) {
  const int tid = threadIdx.x;
  const int floc = tid >> 5, slice = tid & 31;
  const int el = blockIdx.x >> 5;
  const int fg = blockIdx.x & 31;
  const int f = fg * 8 + floc;
  const float w1 = hdr[4];
  const float* src = MT + ((size_t)el * F_ + f) * S_ + slice * 32;
  _Float16* csrow = CS + ((size_t)el * F_ + f) * CSW;
  float aC[NH], aS[NH];
#pragma unroll
  for (int k = 0; k < NH; ++k) { aC[k] = 0.f; aS[k] = 0.f; }
  for (int it = 0; it < 8; ++it) {
    float4 v4 = ((const float4*)src)[it];
    float mv[4] = {v4.x, v4.y, v4.z, v4.w};
#pragma unroll
    for (int c = 0; c < 4; ++c) {
      float al = w1 * mv[c];
      float s1, c1;
      __sincosf(al, &s1, &c1);
      const float tc = 2.f * c1;
      float cp = c1, sp = s1, cpp = 1.f, spp = 0.f;
      aC[0] += c1; aS[0] += s1;
#pragma unroll
      for (int k = 1; k < NH; ++k) {
        float cn = tc * cp - cpp;
        float sn = tc * sp - spp;
        aC[k] += cn; aS[k] += sn;
        cpp = cp; cp = cn; spp = sp; sp = sn;
      }
    }
  }
#pragma unroll
  for (int off = 16; off; off >>= 1)
#pragma unroll
    for (int k = 0; k < NH; ++k) {
      aC[k] += __shfl_down(aC[k], off, 32);
      aS[k] += __shfl_down(aS[k], off, 32);
    }
  if (slice == 0) {
    csrow[0] = (_Float16)1024.f;   // DC: C_0 = S count (exact)
    csrow[1] = (_Float16)0.f;
#pragma unroll
    for (int k = 0; k < NH; ++k) {
      put_hl(csrow + 2 * (1 + k), aC[k]);        // cos harmonics 1..48
      put_hl(csrow + 2 * (NH + 1 + k), aS[k]);   // sin harmonics 1..48
    }
  }
}

// KR: reconstruction GEMM ksum = CS x BT^T via MFMA (7 K-chunks of 32).
// Block = (el, t-tile of 64); wave w owns f in [64w,64w+64): 4x4 16x16 tiles.
__global__ __launch_bounds__(256) void kR(const _Float16* __restrict__ CS,
                                          const _Float16* __restrict__ BT,
                                          float* __restrict__ OUT) {
  __shared__ __align__(16) _Float16 Wl[256][40];
  const int tid = threadIdx.x;
  const int wave = tid >> 6, lane = tid & 63;
  const int nn = lane & 15, quad = lane >> 4;
  const int el = blockIdx.x >> 4;
  const int t0 = (blockIdx.x & 15) << 6;
  const _Float16* Ap = CS + (size_t)el * F_ * CSW;
  f32x4v acc[4][4];
#pragma unroll
  for (int ft = 0; ft < 4; ++ft)
#pragma unroll
    for (int tn = 0; tn < 4; ++tn) acc[ft][tn] = (f32x4v){0.f, 0.f, 0.f, 0.f};
  for (int kc = 0; kc < CSW / 32; ++kc) {
    __syncthreads();
    {
      const int4* s = (const int4*)(Ap + (size_t)tid * CSW + kc * 32);
      int4 v0 = s[0], v1 = s[1], v2 = s[2], v3 = s[3];
      int4* d = (int4*)&Wl[tid][0];
      d[0] = v0; d[1] = v1; d[2] = v2; d[3] = v3;
    }
    __syncthreads();
    half8 bf[4];
#pragma unroll
    for (int tn = 0; tn < 4; ++tn)
      bf[tn] = *(const half8*)(BT + (size_t)(t0 + tn * 16 + nn) * CSW + kc * 32 + quad * 8);
#pragma unroll
    for (int ft = 0; ft < 4; ++ft) {
      half8 af = *(const half8*)&Wl[wave * 64 + ft * 16 + nn][quad * 8];
#pragma unroll
      for (int tn = 0; tn < 4; ++tn)
        acc[ft][tn] = __builtin_amdgcn_mfma_f32_16x16x32_f16(af, bf[tn], acc[ft][tn], 0, 0, 0);
    }
  }
  float* Ob = OUT + (size_t)el * F_ * T_ + t0;
#pragma unroll
  for (int ft = 0; ft < 4; ++ft)
#pragma unroll
    for (int tn = 0; tn < 4; ++tn) {
      f32x4v c = acc[ft][tn];
      const int fb = wave * 64 + ft * 16 + quad * 4;
      const int tc = tn * 16 + nn;
      Ob[(size_t)(fb + 0) * T_ + tc] = c[0];
      Ob[(size_t)(fb + 1) * T_ + tc] = c[1];
      Ob[(size_t)(fb + 2) * T_ + tc] = c[2];
      Ob[(size_t)(fb + 3) * T_ + tc] = c[3];
    }
}

// K4: epilogue (unchanged, validated).
__global__ __launch_bounds__(256) void k4_epi(const float* __restrict__ OUT,
                                              const float* __restrict__ hdr,
                                              const float* __restrict__ dl,
                                              float* __restrict__ out) {
  __shared__ float rs[4][6];
  const int tid = threadIdx.x;
  const int l = blockIdx.x >> 8;
  const int f = blockIdx.x & 255;
  const float left = hdr[0], dg = hdr[1], scale = hdr[3];
  const int t = 4 * tid;
  float etv[4];
#pragma unroll
  for (int d = 0; d < 4; ++d) {
    float x = left + (float)(t + d) * dg;
    etv[d] = expf(-8.0f * x * x);
  }
  float red[E_][4];
#pragma unroll
  for (int e = 0; e < E_; ++e) {
    float4 ks = *(const float4*)(OUT + (((size_t)(e * L_ + l)) * F_ + f) * T_ + t);
    const float dlv = dl[e * L_ + l];
    const float zc = (float)S_ - dlv;
    const float idl = 1.0f / dlv;
    red[e][0] = (ks.x - zc * etv[0]) * idl;
    red[e][1] = (ks.y - zc * etv[1]) * idl;
    red[e][2] = (ks.z - zc * etv[2]) * idl;
    red[e][3] = (ks.w - zc * etv[3]) * idl;
  }
  float D[6];
  const int pa[6] = {0, 0, 0, 1, 1, 2};
  const int pb[6] = {1, 2, 3, 2, 3, 3};
#pragma unroll
  for (int p = 0; p < 6; ++p) {
    float s = 0.f;
#pragma unroll
    for (int d = 0; d < 4; ++d) s += fabsf(red[pa[p]][d] - red[pb[p]][d]);
    D[p] = s;
  }
#pragma unroll
  for (int off = 32; off; off >>= 1)
#pragma unroll
    for (int p = 0; p < 6; ++p) D[p] += __shfl_down(D[p], off);
  if ((tid & 63) == 0) {
#pragma unroll
    for (int p = 0; p < 6; ++p) rs[tid >> 6][p] = D[p];
  }
  __syncthreads();
  if (tid == 0) {
    float Tp[6];
#pragma unroll
    for (int p = 0; p < 6; ++p)
      Tp[p] = (rs[0][p] + rs[1][p] + rs[2][p] + rs[3][p]) * scale;
    float test = Tp[0];
#pragma unroll
    for (int p = 1; p < 6; ++p) test = fmaxf(test, Tp[p]);
    float train = fmaxf(fmaxf(Tp[1], Tp[2]), Tp[5]);
    out[l * F_ + f] = train;
    out[L_ * F_ + l * F_ + f] = test;
  }
}

extern "C" void kernel_launch(void* const* d_in, const int* in_sizes, int n_in,
                              void* d_out, int out_size, void* d_ws, size_t ws_size,
                              hipStream_t stream) {
  const float* A  = (const float*)d_in[0];   // matrix (4,10,1024,256)
  const float* dl = (const float*)d_in[1];   // data_len (4,10)
  const float* P  = (const float*)d_in[2];   // params (256,256)
  float* out = (float*)d_out;
  float* ws = (float*)d_ws;
  float* hdr = ws;
  unsigned int* slots = (unsigned int*)(ws + 16);
  float* MT  = ws + OFF_M;                   // fp32 GEMM result (dead after kF)
  float* OUT = ws + OFF_M;                   // OUT aliases MT
  _Float16* CS = (_Float16*)(ws + OFF_CS);
  _Float16* BT = (_Float16*)(ws + OFF_BT);
  _Float16* PT = (_Float16*)(ws + OFF_PT);

  // Determinism under 0xAA ws-poison: zero all f16 regions (pads included).
  (void)hipMemsetAsync(CS, 0, (size_t)40 * F_ * CSW * 2, stream);   // 4.6 MB
  (void)hipMemsetAsync(BT, 0, (size_t)T_ * CSW * 2, stream);
  (void)hipMemsetAsync(PT, 0, (size_t)F_ * F_ * 2, stream);
  (void)hipMemsetAsync(slots, 0xFF, 4, stream);      // min slot neutral
  (void)hipMemsetAsync(slots + 1, 0x00, 4, stream);  // max slot neutral

  k_pt<<<F_, 256, 0, stream>>>(P, PT);
  k0_mfma<<<NROW / 64, 256, 0, stream>>>(A, PT, MT, slots);
  k1_setup<<<1, 64, 0, stream>>>(slots, hdr);
  kB<<<T_, 256, 0, stream>>>(hdr, BT);
  kF<<<(E_ * L_) * 32, 256, 0, stream>>>(MT, hdr, CS);
  kR<<<(E_ * L_) * 16, 256, 0, stream>>>(CS, BT, OUT);
  k4_epi<<<L_ * F_, 256, 0, stream>>>(OUT, hdr, dl, out);
}